// Round 3
// baseline (289.863 us; speedup 1.0000x reference)
//
#include <hip/hip_runtime.h>
#include <stdint.h>

#define RT    2336          // routes
#define RLDS  2016          // routes held in LDS (bf16)
#define RREG  (RT - RLDS)   // 320 routes held in registers (threads 0..319)
#define NTH   512
#define NBLK  2048          // one block per (b,k): b = blk>>1, k = blk&1
#define BATCH 1024
#define SH1   32.0f         // fixed softmax exponent shift, pass 2 (exact: ratio cancels)
#define SH2   64.0f         // fixed softmax exponent shift, pass 3

__device__ __forceinline__ float blo(uint32_t v){ union {uint32_t u; float f;} x; x.u = v << 16;        return x.f; }
__device__ __forceinline__ float bhi(uint32_t v){ union {uint32_t u; float f;} x; x.u = v & 0xffff0000u; return x.f; }
__device__ __forceinline__ uint32_t f2b1(float f){          // fp32 -> bf16 (RNE)
  union {float f; uint32_t u;} x; x.f = f;
  return (x.u + 0x7fffu + ((x.u >> 16) & 1u)) >> 16;
}
__device__ __forceinline__ uint32_t f2b_pack(float a, float b){ return f2b1(a) | (f2b1(b) << 16); }

__device__ __forceinline__ void unpack16(const uint4& lo, const uint4& hi, float* uf){
  uf[0]=blo(lo.x);  uf[1]=bhi(lo.x);  uf[2]=blo(lo.y);  uf[3]=bhi(lo.y);
  uf[4]=blo(lo.z);  uf[5]=bhi(lo.z);  uf[6]=blo(lo.w);  uf[7]=bhi(lo.w);
  uf[8]=blo(hi.x);  uf[9]=bhi(hi.x);  uf[10]=blo(hi.y); uf[11]=bhi(hi.y);
  uf[12]=blo(hi.z); uf[13]=bhi(hi.z); uf[14]=blo(hi.w); uf[15]=bhi(hi.w);
}

// u_ji[o] = sum_i u[b,r,i] * W[k,r,i,o]   fp32 inputs; W row = 64 floats (256 B)
__device__ __forceinline__ void compute_uji_f32(const float* __restrict__ Ub,
                                                const float* __restrict__ Wk,
                                                int r, float* uji){
  float4 u4 = *(const float4*)(Ub + (size_t)r * 4);
  float uf[4] = { u4.x, u4.y, u4.z, u4.w };
  const float4* wp = (const float4*)(Wk + (size_t)r * 64);
  #pragma unroll
  for (int o = 0; o < 16; ++o) uji[o] = 0.f;
  #pragma unroll
  for (int i = 0; i < 4; ++i){
    #pragma unroll
    for (int q = 0; q < 4; ++q){
      float4 w4 = wp[i*4 + q];           // W[k,r,i,4q..4q+3]
      uji[4*q+0] = fmaf(uf[i], w4.x, uji[4*q+0]);
      uji[4*q+1] = fmaf(uf[i], w4.y, uji[4*q+1]);
      uji[4*q+2] = fmaf(uf[i], w4.z, uji[4*q+2]);
      uji[4*q+3] = fmaf(uf[i], w4.w, uji[4*q+3]);
    }
  }
}

// Reduce (l, acc[16]) across the block; tid0 computes s = acc/l, then either
// v = squash(s) into vbuf, or (last pass) writes class logit ||v|| = n/(1+n).
__device__ __forceinline__ void block_merge(float* acc, float l, int tid,
                                            float (*red)[17], float* vbuf,
                                            bool last, float* out_cls){
  #pragma unroll
  for (int off = 32; off > 0; off >>= 1){
    l += __shfl_down(l, off);
    #pragma unroll
    for (int o = 0; o < 16; ++o) acc[o] += __shfl_down(acc[o], off);
  }
  const int lane = tid & 63, wid = tid >> 6;
  if (lane == 0){
    red[wid][0] = l;
    #pragma unroll
    for (int o = 0; o < 16; ++o) red[wid][1+o] = acc[o];
  }
  __syncthreads();
  if (tid == 0){
    float L = 0.f, S[16];
    #pragma unroll
    for (int o = 0; o < 16; ++o) S[o] = 0.f;
    for (int w2 = 0; w2 < 8; ++w2){
      L += red[w2][0];
      #pragma unroll
      for (int o = 0; o < 16; ++o) S[o] += red[w2][1+o];
    }
    float inv = 1.f / L, norm = 0.f;
    #pragma unroll
    for (int o = 0; o < 16; ++o){ S[o] *= inv; norm += S[o]*S[o]; }
    if (last){
      *out_cls = norm / (1.f + norm);                   // ||squash(s)|| = n/(1+n)
    } else {
      float f = sqrtf(norm) / (1.f + norm);             // squash scale on s
      #pragma unroll
      for (int o = 0; o < 16; ++o) vbuf[o] = S[o] * f;
    }
  }
  __syncthreads();
}

__global__ void __launch_bounds__(NTH, 2)
caps_route(const float* __restrict__ U, const float* __restrict__ W,
           float* __restrict__ Out){
  __shared__ uint4 ujilo[RLDS];     // o=0..7  as bf16x8
  __shared__ uint4 ujihi[RLDS];     // o=8..15 as bf16x8
  __shared__ float red[8][17];
  __shared__ float vbuf[16];

  const int tid = threadIdx.x;
  const int bk  = blockIdx.x;
  const int k   = bk & 1;
  const int b   = bk >> 1;

  const float* Ub = U + (size_t)b * (RT * 4);
  const float* Wk = W + (size_t)k * ((size_t)RT * 64);

  float ur[16];    // register-resident route (threads 0..RREG-1)
  float acc[16], vc[16], d1[5], l;

  // ---------------- Phase A: build u_ji; fused pass 1 (uniform weights) ----
  l = 0.f;
  #pragma unroll
  for (int o = 0; o < 16; ++o) acc[o] = 0.f;

  #pragma unroll
  for (int j = 0; j < 4; ++j){
    int r = tid + NTH * j;
    if (r < RLDS){
      float uji[16];
      compute_uji_f32(Ub, Wk, r, uji);
      #pragma unroll
      for (int o = 0; o < 16; ++o) acc[o] += uji[o];
      l += 1.f;
      uint4 lo, hi;
      lo.x = f2b_pack(uji[0], uji[1]);  lo.y = f2b_pack(uji[2], uji[3]);
      lo.z = f2b_pack(uji[4], uji[5]);  lo.w = f2b_pack(uji[6], uji[7]);
      hi.x = f2b_pack(uji[8], uji[9]);  hi.y = f2b_pack(uji[10], uji[11]);
      hi.z = f2b_pack(uji[12], uji[13]); hi.w = f2b_pack(uji[14], uji[15]);
      ujilo[r] = lo; ujihi[r] = hi;
    }
  }
  if (tid < RREG){
    compute_uji_f32(Ub, Wk, RLDS + tid, ur);
    #pragma unroll
    for (int o = 0; o < 16; ++o) acc[o] += ur[o];
    l += 1.f;
  }
  block_merge(acc, l, tid, red, vbuf, false, nullptr);   // v0
  #pragma unroll
  for (int o = 0; o < 16; ++o) vc[o] = vbuf[o];

  // ---------------- Pass 2: d1 = uji.v0 ; c = softmax(d1); s1 -------------
  l = 0.f;
  #pragma unroll
  for (int o = 0; o < 16; ++o) acc[o] = 0.f;
  #pragma unroll
  for (int j = 0; j < 4; ++j){
    int r = tid + NTH * j;
    if (r < RLDS){
      uint4 lo = ujilo[r], hi = ujihi[r];
      float uf[16];
      unpack16(lo, hi, uf);
      float d = 0.f;
      #pragma unroll
      for (int o = 0; o < 16; ++o) d = fmaf(uf[o], vc[o], d);
      d1[j] = d;
      float e = __expf(d - SH1);
      l += e;
      #pragma unroll
      for (int o = 0; o < 16; ++o) acc[o] = fmaf(e, uf[o], acc[o]);
    }
  }
  if (tid < RREG){
    float d = 0.f;
    #pragma unroll
    for (int o = 0; o < 16; ++o) d = fmaf(ur[o], vc[o], d);
    d1[4] = d;
    float e = __expf(d - SH1);
    l += e;
    #pragma unroll
    for (int o = 0; o < 16; ++o) acc[o] = fmaf(e, ur[o], acc[o]);
  }
  block_merge(acc, l, tid, red, vbuf, false, nullptr);   // v1
  #pragma unroll
  for (int o = 0; o < 16; ++o) vc[o] = vbuf[o];

  // ---------------- Pass 3: b2 = d1 + uji.v1 ; c = softmax; s2 ------------
  l = 0.f;
  #pragma unroll
  for (int o = 0; o < 16; ++o) acc[o] = 0.f;
  #pragma unroll
  for (int j = 0; j < 4; ++j){
    int r = tid + NTH * j;
    if (r < RLDS){
      uint4 lo = ujilo[r], hi = ujihi[r];
      float uf[16];
      unpack16(lo, hi, uf);
      float d = d1[j];
      #pragma unroll
      for (int o = 0; o < 16; ++o) d = fmaf(uf[o], vc[o], d);
      float e = __expf(d - SH2);
      l += e;
      #pragma unroll
      for (int o = 0; o < 16; ++o) acc[o] = fmaf(e, uf[o], acc[o]);
    }
  }
  if (tid < RREG){
    float d = d1[4];
    #pragma unroll
    for (int o = 0; o < 16; ++o) d = fmaf(ur[o], vc[o], d);
    float e = __expf(d - SH2);
    l += e;
    #pragma unroll
    for (int o = 0; o < 16; ++o) acc[o] = fmaf(e, ur[o], acc[o]);
  }
  block_merge(acc, l, tid, red, vbuf, true, Out + bk);   // logit -> Out[b*2+k]
}

// In-place 2-way softmax over k: Out[b,0..1] fp32
__global__ void caps_softmax(float* __restrict__ Out){
  int b = blockIdx.x * blockDim.x + threadIdx.x;
  if (b < BATCH){
    float2* p = (float2*)Out;
    float2 c = p[b];
    float m  = fmaxf(c.x, c.y);
    float e0 = __expf(c.x - m), e1 = __expf(c.y - m);
    float inv = 1.f / (e0 + e1);
    p[b] = make_float2(e0 * inv, e1 * inv);
  }
}

extern "C" void kernel_launch(void* const* d_in, const int* in_sizes, int n_in,
                              void* d_out, int out_size, void* d_ws, size_t ws_size,
                              hipStream_t stream) {
  const float* U = (const float*)d_in[0];   // [1024, 2336, 4] fp32
  const float* W = (const float*)d_in[1];   // [2, 2336, 4, 16] fp32
  float* Out = (float*)d_out;               // [1024, 2] fp32
  caps_route<<<dim3(NBLK), dim3(NTH), 0, stream>>>(U, W, Out);
  caps_softmax<<<dim3(BATCH / 256), dim3(256), 0, stream>>>(Out);
}

// Round 4
// 152.033 us; speedup vs baseline: 1.9066x; 1.9066x over previous
//
#include <hip/hip_runtime.h>
#include <stdint.h>

#define RT    2336          // routes
#define RLDS  1952          // routes resident in LDS (bf16 quads, 8 B/slice)
#define RRES  (RT - RLDS)   // 384 residue routes: 3 register slices per thread
#define NTH   512
#define NBLK  2048          // one block per (b,k): b = blk>>1, k = blk&1
#define BATCH 1024
#define SH1   32.0f         // fixed softmax exponent shift, pass 2 (exact: ratio cancels)
#define SH2   64.0f         // fixed softmax exponent shift, pass 3

__device__ __forceinline__ float blo(uint32_t v){ union {uint32_t u; float f;} x; x.u = v << 16;        return x.f; }
__device__ __forceinline__ float bhi(uint32_t v){ union {uint32_t u; float f;} x; x.u = v & 0xffff0000u; return x.f; }
__device__ __forceinline__ uint32_t f2b1(float f){          // fp32 -> bf16 (RNE)
  union {float f; uint32_t u;} x; x.f = f;
  return (x.u + 0x7fffu + ((x.u >> 16) & 1u)) >> 16;
}
__device__ __forceinline__ uint32_t f2b_pack(float a, float b){ return f2b1(a) | (f2b1(b) << 16); }

// Quad-layout block merge: each lane holds (l, a[4]) for its o-quad qo = tid&3.
// Reduces over lanes with equal tid%4, then tid0 finishes: s = acc/L, squash.
__device__ __forceinline__ void merge_quad(float4& a, float l, int tid,
                                           float (*red)[4][5], float* vbuf,
                                           bool last, float* out_cls){
  #pragma unroll
  for (int off = 32; off >= 4; off >>= 1){
    a.x += __shfl_down(a.x, off); a.y += __shfl_down(a.y, off);
    a.z += __shfl_down(a.z, off); a.w += __shfl_down(a.w, off);
    l   += __shfl_down(l,   off);
  }
  const int lane = tid & 63, wid = tid >> 6;
  if (lane < 4){
    red[wid][lane][0] = l;
    red[wid][lane][1] = a.x; red[wid][lane][2] = a.y;
    red[wid][lane][3] = a.z; red[wid][lane][4] = a.w;
  }
  __syncthreads();
  if (tid == 0){
    float L = 0.f, S[16];
    #pragma unroll
    for (int o = 0; o < 16; ++o) S[o] = 0.f;
    for (int w = 0; w < 8; ++w){
      #pragma unroll
      for (int q = 0; q < 4; ++q){
        L += red[w][q][0];
        #pragma unroll
        for (int j = 0; j < 4; ++j) S[4*q+j] += red[w][q][1+j];
      }
    }
    L *= 0.25f;                       // each route counted once per qo-class
    float inv = 1.f / L, norm = 0.f;
    #pragma unroll
    for (int o = 0; o < 16; ++o){ S[o] *= inv; norm += S[o]*S[o]; }
    if (last){
      *out_cls = norm / (1.f + norm);                 // ||squash(s)|| = n/(1+n)
    } else {
      float f = sqrtf(norm) / (1.f + norm);           // squash scale on s
      #pragma unroll
      for (int o = 0; o < 16; ++o) vbuf[o] = S[o] * f;
    }
  }
  __syncthreads();
}

__global__ void __launch_bounds__(NTH, 4)
caps_route(const float* __restrict__ U, const float* __restrict__ W,
           float* __restrict__ Out){
  __shared__ uint2 uj[RLDS * 4];      // slice idx = route*4 + qo : bf16x4
  __shared__ float red[8][4][5];
  __shared__ float vbuf[16];

  const int tid = threadIdx.x;
  const int qo  = tid & 3;            // my o-quad: o = 4*qo .. 4*qo+3
  const int k   = blockIdx.x & 1;
  const int b   = blockIdx.x >> 1;

  const float* Ub = U + (size_t)b * (RT * 4);
  const float* Wk = W + (size_t)k * ((size_t)RT * 64) + qo * 4;

  float4 acc; float l;
  float  ur[3][4];                    // residue slices (routes RLDS..RT-1)
  float  d1[16], d1r[3];              // pass-2 dots, carried into pass 3
  float  vc0, vc1, vc2, vc3;          // my quad of v

  // u_ji quad for route r: uji[4qo+j] = sum_i u[b,r,i] * W[k,r,i,4qo+j]
  // W loads: lane stride 16 B inside 64-B lines -> fully coalesced.
  auto build_rq = [&](int route) -> float4 {
    float4 u4 = *(const float4*)(Ub + (size_t)route * 4);
    const float* wr = Wk + (size_t)route * 64;
    float4 w0 = *(const float4*)(wr);
    float4 w1 = *(const float4*)(wr + 16);
    float4 w2 = *(const float4*)(wr + 32);
    float4 w3 = *(const float4*)(wr + 48);
    float4 p;
    p.x = u4.x * w0.x; p.y = u4.x * w0.y; p.z = u4.x * w0.z; p.w = u4.x * w0.w;
    p.x = fmaf(u4.y, w1.x, p.x); p.y = fmaf(u4.y, w1.y, p.y);
    p.z = fmaf(u4.y, w1.z, p.z); p.w = fmaf(u4.y, w1.w, p.w);
    p.x = fmaf(u4.z, w2.x, p.x); p.y = fmaf(u4.z, w2.y, p.y);
    p.z = fmaf(u4.z, w2.z, p.z); p.w = fmaf(u4.z, w2.w, p.w);
    p.x = fmaf(u4.w, w3.x, p.x); p.y = fmaf(u4.w, w3.y, p.y);
    p.z = fmaf(u4.w, w3.z, p.z); p.w = fmaf(u4.w, w3.w, p.w);
    return p;
  };

  // ---------------- Phase A: build u_ji; fused pass 1 (uniform weights) ----
  acc = make_float4(0.f, 0.f, 0.f, 0.f); l = 0.f;

  if (tid < 128){                     // pre-step: routes 0..31
    int route = tid >> 2;
    float4 p = build_rq(route);
    acc.x += p.x; acc.y += p.y; acc.z += p.z; acc.w += p.w; l += 1.f;
    uj[route*4 + qo] = make_uint2(f2b_pack(p.x, p.y), f2b_pack(p.z, p.w));
  }
  #pragma unroll 3
  for (int s = 0; s < 18; ++s){       // routes 32 + 128*s + tid/4
    int route = 32 + s*128 + (tid >> 2);
    float4 p = build_rq(route);
    acc.x += p.x; acc.y += p.y; acc.z += p.z; acc.w += p.w; l += 1.f;
    if (s < 15){
      uj[route*4 + qo] = make_uint2(f2b_pack(p.x, p.y), f2b_pack(p.z, p.w));
    } else {
      int slot = s - 15;              // routes 1952..2335 stay in registers
      ur[slot][0] = p.x; ur[slot][1] = p.y; ur[slot][2] = p.z; ur[slot][3] = p.w;
    }
  }
  merge_quad(acc, l, tid, red, vbuf, false, nullptr);   // v0
  vc0 = vbuf[4*qo]; vc1 = vbuf[4*qo+1]; vc2 = vbuf[4*qo+2]; vc3 = vbuf[4*qo+3];

  // ---------------- Pass 2: d = uji.v0 ; c = softmax(d); s1 ---------------
  acc = make_float4(0.f, 0.f, 0.f, 0.f); l = 0.f;
  #pragma unroll 4
  for (int s = 0; s < 16; ++s){       // LDS slices, idx = tid + 512*s
    int idx = tid + (s << 9);
    bool act = (idx < RLDS * 4);      // only s==15 is partial (tid<128)
    float uf0=0.f, uf1=0.f, uf2=0.f, uf3=0.f, d = 0.f;
    if (act){
      uint2 q2 = uj[idx];
      uf0 = blo(q2.x); uf1 = bhi(q2.x); uf2 = blo(q2.y); uf3 = bhi(q2.y);
      d = fmaf(uf0, vc0, fmaf(uf1, vc1, fmaf(uf2, vc2, uf3 * vc3)));
    }
    d += __shfl_xor(d, 1); d += __shfl_xor(d, 2);   // full route dot to all 4 lanes
    d1[s] = d;
    if (act){
      float e = __expf(d - SH1);
      l += e;
      acc.x = fmaf(e, uf0, acc.x); acc.y = fmaf(e, uf1, acc.y);
      acc.z = fmaf(e, uf2, acc.z); acc.w = fmaf(e, uf3, acc.w);
    }
  }
  #pragma unroll
  for (int slot = 0; slot < 3; ++slot){             // residue slices
    float d = fmaf(ur[slot][0], vc0, fmaf(ur[slot][1], vc1,
              fmaf(ur[slot][2], vc2, ur[slot][3] * vc3)));
    d += __shfl_xor(d, 1); d += __shfl_xor(d, 2);
    d1r[slot] = d;
    float e = __expf(d - SH1);
    l += e;
    acc.x = fmaf(e, ur[slot][0], acc.x); acc.y = fmaf(e, ur[slot][1], acc.y);
    acc.z = fmaf(e, ur[slot][2], acc.z); acc.w = fmaf(e, ur[slot][3], acc.w);
  }
  merge_quad(acc, l, tid, red, vbuf, false, nullptr);   // v1
  vc0 = vbuf[4*qo]; vc1 = vbuf[4*qo+1]; vc2 = vbuf[4*qo+2]; vc3 = vbuf[4*qo+3];

  // ---------------- Pass 3: b2 = d1 + uji.v1 ; c = softmax; s2 ------------
  acc = make_float4(0.f, 0.f, 0.f, 0.f); l = 0.f;
  #pragma unroll 4
  for (int s = 0; s < 16; ++s){
    int idx = tid + (s << 9);
    bool act = (idx < RLDS * 4);
    float uf0=0.f, uf1=0.f, uf2=0.f, uf3=0.f, d = 0.f;
    if (act){
      uint2 q2 = uj[idx];
      uf0 = blo(q2.x); uf1 = bhi(q2.x); uf2 = blo(q2.y); uf3 = bhi(q2.y);
      d = fmaf(uf0, vc0, fmaf(uf1, vc1, fmaf(uf2, vc2, uf3 * vc3)));
    }
    d += __shfl_xor(d, 1); d += __shfl_xor(d, 2);
    d += d1[s];
    if (act){
      float e = __expf(d - SH2);
      l += e;
      acc.x = fmaf(e, uf0, acc.x); acc.y = fmaf(e, uf1, acc.y);
      acc.z = fmaf(e, uf2, acc.z); acc.w = fmaf(e, uf3, acc.w);
    }
  }
  #pragma unroll
  for (int slot = 0; slot < 3; ++slot){
    float d = fmaf(ur[slot][0], vc0, fmaf(ur[slot][1], vc1,
              fmaf(ur[slot][2], vc2, ur[slot][3] * vc3)));
    d += __shfl_xor(d, 1); d += __shfl_xor(d, 2);
    d += d1r[slot];
    float e = __expf(d - SH2);
    l += e;
    acc.x = fmaf(e, ur[slot][0], acc.x); acc.y = fmaf(e, ur[slot][1], acc.y);
    acc.z = fmaf(e, ur[slot][2], acc.z); acc.w = fmaf(e, ur[slot][3], acc.w);
  }
  merge_quad(acc, l, tid, red, vbuf, true, Out + blockIdx.x);  // logit -> Out[b*2+k]
}

// In-place 2-way softmax over k: Out[b,0..1] fp32
__global__ void caps_softmax(float* __restrict__ Out){
  int b = blockIdx.x * blockDim.x + threadIdx.x;
  if (b < BATCH){
    float2* p = (float2*)Out;
    float2 c = p[b];
    float m  = fmaxf(c.x, c.y);
    float e0 = __expf(c.x - m), e1 = __expf(c.y - m);
    float inv = 1.f / (e0 + e1);
    p[b] = make_float2(e0 * inv, e1 * inv);
  }
}

extern "C" void kernel_launch(void* const* d_in, const int* in_sizes, int n_in,
                              void* d_out, int out_size, void* d_ws, size_t ws_size,
                              hipStream_t stream) {
  const float* U = (const float*)d_in[0];   // [1024, 2336, 4] fp32
  const float* W = (const float*)d_in[1];   // [2, 2336, 4, 16] fp32
  float* Out = (float*)d_out;               // [1024, 2] fp32
  caps_route<<<dim3(NBLK), dim3(NTH), 0, stream>>>(U, W, Out);
  caps_softmax<<<dim3(BATCH / 256), dim3(256), 0, stream>>>(Out);
}